// Round 6
// baseline (141.966 us; speedup 1.0000x reference)
//
#include <hip/hip_runtime.h>

#define F_IN 128
#define CH   128

typedef __attribute__((ext_vector_type(8))) short bf16x8;
typedef __attribute__((ext_vector_type(4))) float f32x4;
typedef __attribute__((ext_vector_type(2))) float f32x2;
typedef __attribute__((ext_vector_type(4))) unsigned u32x4;

// f32 -> bf16 round-to-nearest-even
static __device__ __forceinline__ ushort f2b(float f) {
  union { float f; unsigned u; } v; v.f = f;
  const unsigned u = v.u;
  return (ushort)((u + 0x7FFFu + ((u >> 16) & 1u)) >> 16);
}

// ---------------------------------------------------------------------------
// Phase 1 (fused): blocks [0, gemm_blocks) do XW = X @ W via bf16 MFMA,
//   then quantize each output row to int8 (offset-binary, per-node scale
//   s[r] = rowmax/127) -> 12.8 MB table + 400 KB scales.
// blocks [gemm_blocks, ...) do row_ptr[r] = lower_bound(edge_row, r).
// mfma_f32_16x16x32_bf16 layouts (guide §3, m89-verified):
//   A frag: row = lane&15, k = (lane>>4)*8 + j
//   B frag: col = lane&15, k = (lane>>4)*8 + j
//   C/D   : col = lane&15, row = (lane>>4)*4 + reg
// ---------------------------------------------------------------------------
__global__ __launch_bounds__(512) void gemm_rowptr_fused(
    const float* __restrict__ x, const float* __restrict__ w,
    unsigned char* __restrict__ xwq, float* __restrict__ scale,
    const int* __restrict__ edge_row, int* __restrict__ row_ptr,
    int n, int n_edges, int gemm_blocks) {
  __shared__ __align__(16) ushort Wt[F_IN * CH];  // W^T, swizzled, 32 KB
  const int t = threadIdx.x;

  if ((int)blockIdx.x >= gemm_blocks) {
    // ---- rowptr tail blocks: CSR offsets from sorted edge_row ----
    const int r = ((int)blockIdx.x - gemm_blocks) * 512 + t;
    if (r <= n) {
      int lo = 0, hi = n_edges;
      while (lo < hi) {
        const int mid = (lo + hi) >> 1;
        if (edge_row[mid] < r) lo = mid + 1; else hi = mid;
      }
      row_ptr[r] = lo;
    }
    return;
  }

  // ---- GEMM blocks ----
  // stage W^T as bf16 with XOR swizzle: byte ^= (col&7)<<4
  for (int i = t; i < (F_IN * CH) / 4; i += 512) {
    const int k  = i >> 5;          // 0..127
    const int n4 = (i & 31) << 2;   // 0,4,...,124
    const f32x4 wv = *(const f32x4*)&w[k * CH + n4];
#pragma unroll
    for (int q = 0; q < 4; ++q) {
      const int nn = n4 + q;
      const int byte = (nn * 256 + k * 2) ^ ((nn & 7) << 4);
      *(ushort*)((char*)Wt + byte) = f2b(wv[q]);
    }
  }
  __syncthreads();

  const int wave = t >> 6, lane = t & 63;
  const int R0   = blockIdx.x * 128 + wave * 16;
  const int arow = R0 + (lane & 15);
  const int kgrp = (lane >> 4) * 8;

  // A fragments (4 K-steps), f32->bf16 in-register; x is read-once -> nt loads
  bf16x8 a[4];
#pragma unroll
  for (int s = 0; s < 4; ++s) {
    if (arow < n) {
      const f32x4 p0 = __builtin_nontemporal_load(
          (const f32x4*)&x[arow * F_IN + s * 32 + kgrp]);
      const f32x4 p1 = __builtin_nontemporal_load(
          (const f32x4*)&x[arow * F_IN + s * 32 + kgrp + 4]);
#pragma unroll
      for (int j = 0; j < 4; ++j) {
        a[s][j]     = (short)f2b(p0[j]);
        a[s][j + 4] = (short)f2b(p1[j]);
      }
    } else {
#pragma unroll
      for (int j = 0; j < 8; ++j) a[s][j] = (short)0;
    }
  }

  f32x4 acc[8];
#pragma unroll
  for (int t8 = 0; t8 < 8; ++t8) acc[t8] = (f32x4){0.f, 0.f, 0.f, 0.f};

#pragma unroll
  for (int t8 = 0; t8 < 8; ++t8) {
    const int col = t8 * 16 + (lane & 15);
#pragma unroll
    for (int s = 0; s < 4; ++s) {
      const int byte = (col * 256 + (s * 32 + kgrp) * 2) ^ ((col & 7) << 4);
      const bf16x8 b = *(const bf16x8*)((const char*)Wt + byte);
      acc[t8] = __builtin_amdgcn_mfma_f32_16x16x32_bf16(a[s], b, acc[t8], 0, 0, 0);
    }
  }

  // Epilogue: per-row absmax (shfl over the 16 channel-lanes) -> int8 quant.
  const int li = lane & 15;
  const int r0 = R0 + (lane >> 4) * 4;
#pragma unroll
  for (int i = 0; i < 4; ++i) {
    const int rr = r0 + i;
    float m = 0.f;
#pragma unroll
    for (int t8 = 0; t8 < 8; ++t8) m = fmaxf(m, fabsf(acc[t8][i]));
    m = fmaxf(m, __shfl_xor(m, 1));
    m = fmaxf(m, __shfl_xor(m, 2));
    m = fmaxf(m, __shfl_xor(m, 4));
    m = fmaxf(m, __shfl_xor(m, 8));
    const float inv = (m > 1e-20f) ? 127.f / m : 0.f;
    if (rr < n) {
      if (li == 0) scale[rr] = m * (1.f / 127.f);
#pragma unroll
      for (int t8 = 0; t8 < 8; ++t8) {
        // |acc|*inv <= 127 by construction; +128 -> [1,255], no clamp needed
        const float q = rintf(acc[t8][i] * inv) + 128.f;
        xwq[rr * CH + t8 * 16 + li] = (unsigned char)q;
      }
    }
  }
}

// ---------------------------------------------------------------------------
// Phase 2: SpMM on the int8 table. TWO rows per wave, software-pipelined
// (R5 lesson: per-row latency chain meta->gather->decode->butterfly was the
// stall; B's gathers are in flight during A's decode/reduce).
// Per row: 64-edge superblock, each lane owns one edge's meta; 8 lanes x
// u32x4 (16B) gather per 128B int8 row, batch-issued unconditionally
// (dummy slots hit hot row 0); decode early-exits wave-uniformly; f32x2
// pk_fma decode. -128 offset folded into scalar S. Butterfly xor 8/16/32.
// Rows with deg>64 (probability ~0 at mean 32) take a sequential slow path.
// ---------------------------------------------------------------------------
#define ACCD(A2, word, j0, vv)                                            \
  do {                                                                    \
    f32x2 lo_, hi_;                                                       \
    lo_[0] = (float)((word) & 0xFFu);                                     \
    lo_[1] = (float)(((word) >> 8) & 0xFFu);                              \
    hi_[0] = (float)(((word) >> 16) & 0xFFu);                             \
    hi_[1] = (float)((word) >> 24);                                       \
    (A2)[(j0)]     = __builtin_elementwise_fma(vv, lo_, (A2)[(j0)]);      \
    (A2)[(j0) + 1] = __builtin_elementwise_fma(vv, hi_, (A2)[(j0) + 1]);  \
  } while (0)

#define ACC16PK(A2, U, V)                                                 \
  do {                                                                    \
    const f32x2 vv_ = {(V), (V)};                                         \
    ACCD(A2, (U)[0], 0, vv_);                                             \
    ACCD(A2, (U)[1], 2, vv_);                                             \
    ACCD(A2, (U)[2], 4, vv_);                                             \
    ACCD(A2, (U)[3], 6, vv_);                                             \
  } while (0)

// Reduce acc2 over the 8 edge-subgroups, reduce S over all lanes, then
// bias+ReLU store (g8==0 lanes). Must be called wave-uniformly.
static __device__ __forceinline__ void reduce_store(
    f32x2* acc2, float S, const float* __restrict__ bias,
    float* __restrict__ out, int row, int g8, int l8) {
  S += __shfl_xor(S, 1);
  S += __shfl_xor(S, 2);
  S += __shfl_xor(S, 4);
  S += __shfl_xor(S, 8);
  S += __shfl_xor(S, 16);
  S += __shfl_xor(S, 32);
  float* acc = (float*)acc2;
#pragma unroll
  for (int j = 0; j < 16; ++j) {
    acc[j] += __shfl_xor(acc[j], 8);
    acc[j] += __shfl_xor(acc[j], 16);
    acc[j] += __shfl_xor(acc[j], 32);
  }
  if (g8 == 0) {
    const int c = l8 * 16;
    const float off = 128.f * S;
#pragma unroll
    for (int q = 0; q < 4; ++q) {
      const f32x4 bv = *(const f32x4*)&bias[c + q * 4];
      f32x4 o;
      o[0] = fmaxf(acc[q * 4 + 0] - off + bv[0], 0.f);
      o[1] = fmaxf(acc[q * 4 + 1] - off + bv[1], 0.f);
      o[2] = fmaxf(acc[q * 4 + 2] - off + bv[2], 0.f);
      o[3] = fmaxf(acc[q * 4 + 3] - off + bv[3], 0.f);
      __builtin_nontemporal_store(o, (f32x4*)&out[(size_t)row * CH + c + q * 4]);
    }
  }
}

// General (multi-superblock) row path — R5 structure. Rarely taken.
static __device__ __forceinline__ void spmm_row_slow(
    const u32x4* __restrict__ xw4, const float* __restrict__ scale,
    const float* __restrict__ edge_val, const int* __restrict__ edge_col,
    const float* __restrict__ bias, float* __restrict__ out,
    int row, int start, int end, int lane, int g8, int l8) {
  f32x2 acc2[8];
#pragma unroll
  for (int j = 0; j < 8; ++j) acc2[j] = (f32x2){0.f, 0.f};
  float S = 0.f;

  for (int e0 = start; e0 < end; e0 += 64) {
    const int e = e0 + lane;
    int   c_my = 0;
    float vp_my = 0.f;
    if (e < end) {
      c_my = __builtin_nontemporal_load(edge_col + e);
      const float v = __builtin_nontemporal_load(edge_val + e);
      vp_my = v * scale[c_my];
    }
    S += vp_my;

    u32x4 u[8];
#pragma unroll
    for (int it = 0; it < 8; ++it) {
      const int c = __shfl(c_my, it * 8 + g8);
      u[it] = xw4[c * 8 + l8];
    }
#pragma unroll
    for (int it = 0; it < 8; ++it) {
      if (e0 + it * 8 >= end) break;
      const float vp = __shfl(vp_my, it * 8 + g8);
      ACC16PK(acc2, u[it], vp);
    }
  }
  reduce_store(acc2, S, bias, out, row, g8, l8);
}

__global__ __launch_bounds__(256) void spmm_rowwave2(
    const unsigned char* __restrict__ xwq, const float* __restrict__ scale,
    const float* __restrict__ edge_val, const int* __restrict__ edge_col,
    const int* __restrict__ row_ptr, const float* __restrict__ bias,
    float* __restrict__ out, int n) {
  const int pair = (int)((blockIdx.x * blockDim.x + threadIdx.x) >> 6);
  const int rA = pair * 2;
  if (rA >= n) return;
  const int rB = rA + 1;
  const bool okB = (rB < n);
  const int lane = threadIdx.x & 63;
  const int g8 = lane >> 3;   // edge subgroup 0..7
  const int l8 = lane & 7;    // channel chunk: channels l8*16 .. l8*16+15
  const u32x4* __restrict__ xw4 = (const u32x4*)xwq;  // 8 u32x4 per row

  const int sA = row_ptr[rA], eA = row_ptr[rA + 1];
  const int sB = okB ? row_ptr[rB] : 0;
  const int eB = okB ? row_ptr[rB + 1] : 0;
  const int dA = eA - sA, dB = eB - sB;

  if (dA <= 64 && dB <= 64) {
    // ---------------- fast path: both rows fit one superblock ----------------
    // meta A / meta B (independent VMEM chains)
    int cA = 0; float vpA = 0.f;
    if (lane < dA) {
      const int e = sA + lane;
      cA = __builtin_nontemporal_load(edge_col + e);
      vpA = __builtin_nontemporal_load(edge_val + e) * scale[cA];
    }
    int cB = 0; float vpB = 0.f;
    if (lane < dB) {
      const int e = sB + lane;
      cB = __builtin_nontemporal_load(edge_col + e);
      vpB = __builtin_nontemporal_load(edge_val + e) * scale[cB];
    }

    // batch-issue all 16 gathers (8 per row) unconditionally: decodeA runs
    // with uB's gathers still in flight (counted vmcnt), hiding their latency
    u32x4 uA[8], uB[8];
#pragma unroll
    for (int it = 0; it < 8; ++it) {
      const int c = __shfl(cA, it * 8 + g8);
      uA[it] = xw4[c * 8 + l8];
    }
#pragma unroll
    for (int it = 0; it < 8; ++it) {
      const int c = __shfl(cB, it * 8 + g8);
      uB[it] = xw4[c * 8 + l8];
    }

    f32x2 accA[8];
#pragma unroll
    for (int j = 0; j < 8; ++j) accA[j] = (f32x2){0.f, 0.f};
#pragma unroll
    for (int it = 0; it < 8; ++it) {
      if (it * 8 >= dA) break;
      const float vp = __shfl(vpA, it * 8 + g8);
      ACC16PK(accA, uA[it], vp);
    }
    reduce_store(accA, vpA, bias, out, rA, g8, l8);

    f32x2 accB[8];
#pragma unroll
    for (int j = 0; j < 8; ++j) accB[j] = (f32x2){0.f, 0.f};
#pragma unroll
    for (int it = 0; it < 8; ++it) {
      if (it * 8 >= dB) break;
      const float vp = __shfl(vpB, it * 8 + g8);
      ACC16PK(accB, uB[it], vp);
    }
    if (okB) reduce_store(accB, vpB, bias, out, rB, g8, l8);
  } else {
    // ---------------- slow path: sequential general rows ----------------
    spmm_row_slow(xw4, scale, edge_val, edge_col, bias, out, rA, sA, eA,
                  lane, g8, l8);
    if (okB)
      spmm_row_slow(xw4, scale, edge_val, edge_col, bias, out, rB, sB, eB,
                    lane, g8, l8);
  }
}

extern "C" void kernel_launch(void* const* d_in, const int* in_sizes, int n_in,
                              void* d_out, int out_size, void* d_ws, size_t ws_size,
                              hipStream_t stream) {
  const float* x        = (const float*)d_in[0];
  const float* kernel   = (const float*)d_in[1];
  const float* bias     = (const float*)d_in[2];
  const float* edge_val = (const float*)d_in[3];
  const int*   edge_row = (const int*)d_in[4];
  const int*   edge_col = (const int*)d_in[5];
  float* out = (float*)d_out;

  const int n       = in_sizes[0] / F_IN;   // 100000
  const int n_edges = in_sizes[3];          // 3200000

  // ws layout: [xwq: n*CH int8 = 12.8 MB][scale: n f32][row_ptr: (n+1) int]
  unsigned char* xwq = (unsigned char*)d_ws;
  float* scale = (float*)((char*)d_ws + (size_t)n * CH);
  int* rowptr  = (int*)((char*)d_ws + (size_t)n * CH + (size_t)n * sizeof(float));

  // Phase 1 (fused): XW = X @ W (bf16 MFMA) + int8 quant + CSR row_ptr
  const int GB = (n + 127) / 128;
  const int RB = (n + 1 + 511) / 512;
  gemm_rowptr_fused<<<GB + RB, 512, 0, stream>>>(x, kernel, xwq, scale,
                                                 edge_row, rowptr,
                                                 n, n_edges, GB);

  // Phase 2: SpMM + bias + ReLU. Two rows per wave, pipelined.
  const int pairs  = (n + 1) / 2;
  const int blocks = (pairs + 3) / 4;   // 4 waves per 256-thr block
  spmm_rowwave2<<<blocks, 256, 0, stream>>>(xwq, scale, edge_val, edge_col,
                                            rowptr, bias, out, n);
}

// Round 7
// 112.546 us; speedup vs baseline: 1.2614x; 1.2614x over previous
//
#include <hip/hip_runtime.h>

#define F_IN 128
#define CH   128

typedef __attribute__((ext_vector_type(8))) short bf16x8;
typedef __attribute__((ext_vector_type(4))) float f32x4;
typedef __attribute__((ext_vector_type(2))) float f32x2;
typedef __attribute__((ext_vector_type(2))) unsigned u32x2;

// f32 -> bf16 round-to-nearest-even
static __device__ __forceinline__ ushort f2b(float f) {
  union { float f; unsigned u; } v; v.f = f;
  const unsigned u = v.u;
  return (ushort)((u + 0x7FFFu + ((u >> 16) & 1u)) >> 16);
}

// ---------------------------------------------------------------------------
// Phase 1 (fused): blocks [0, gemm_blocks) do XW = X @ W via bf16 MFMA,
//   then quantize each output row to int8 (offset-binary, per-node scale
//   s[r] = rowmax/127) -> 12.8 MB table + 400 KB scales.
// blocks [gemm_blocks, ...) do row_ptr[r] = lower_bound(edge_row, r).
// mfma_f32_16x16x32_bf16 layouts (guide §3, m89-verified):
//   A frag: row = lane&15, k = (lane>>4)*8 + j
//   B frag: col = lane&15, k = (lane>>4)*8 + j
//   C/D   : col = lane&15, row = (lane>>4)*4 + reg
// ---------------------------------------------------------------------------
__global__ __launch_bounds__(512) void gemm_rowptr_fused(
    const float* __restrict__ x, const float* __restrict__ w,
    unsigned char* __restrict__ xwq, float* __restrict__ scale,
    const int* __restrict__ edge_row, int* __restrict__ row_ptr,
    int n, int n_edges, int gemm_blocks) {
  __shared__ __align__(16) ushort Wt[F_IN * CH];  // W^T, swizzled, 32 KB
  const int t = threadIdx.x;

  if ((int)blockIdx.x >= gemm_blocks) {
    // ---- rowptr tail blocks: CSR offsets from sorted edge_row ----
    const int r = ((int)blockIdx.x - gemm_blocks) * 512 + t;
    if (r <= n) {
      int lo = 0, hi = n_edges;
      while (lo < hi) {
        const int mid = (lo + hi) >> 1;
        if (edge_row[mid] < r) lo = mid + 1; else hi = mid;
      }
      row_ptr[r] = lo;
    }
    return;
  }

  // ---- GEMM blocks ----
  // stage W^T as bf16 with XOR swizzle: byte ^= (col&7)<<4
  for (int i = t; i < (F_IN * CH) / 4; i += 512) {
    const int k  = i >> 5;          // 0..127
    const int n4 = (i & 31) << 2;   // 0,4,...,124
    const f32x4 wv = *(const f32x4*)&w[k * CH + n4];
#pragma unroll
    for (int q = 0; q < 4; ++q) {
      const int nn = n4 + q;
      const int byte = (nn * 256 + k * 2) ^ ((nn & 7) << 4);
      *(ushort*)((char*)Wt + byte) = f2b(wv[q]);
    }
  }
  __syncthreads();

  const int wave = t >> 6, lane = t & 63;
  const int R0   = blockIdx.x * 128 + wave * 16;
  const int arow = R0 + (lane & 15);
  const int kgrp = (lane >> 4) * 8;

  // A fragments (4 K-steps), f32->bf16 in-register; x is read-once -> nt loads
  bf16x8 a[4];
#pragma unroll
  for (int s = 0; s < 4; ++s) {
    if (arow < n) {
      const f32x4 p0 = __builtin_nontemporal_load(
          (const f32x4*)&x[arow * F_IN + s * 32 + kgrp]);
      const f32x4 p1 = __builtin_nontemporal_load(
          (const f32x4*)&x[arow * F_IN + s * 32 + kgrp + 4]);
#pragma unroll
      for (int j = 0; j < 4; ++j) {
        a[s][j]     = (short)f2b(p0[j]);
        a[s][j + 4] = (short)f2b(p1[j]);
      }
    } else {
#pragma unroll
      for (int j = 0; j < 8; ++j) a[s][j] = (short)0;
    }
  }

  f32x4 acc[8];
#pragma unroll
  for (int t8 = 0; t8 < 8; ++t8) acc[t8] = (f32x4){0.f, 0.f, 0.f, 0.f};

#pragma unroll
  for (int t8 = 0; t8 < 8; ++t8) {
    const int col = t8 * 16 + (lane & 15);
#pragma unroll
    for (int s = 0; s < 4; ++s) {
      const int byte = (col * 256 + (s * 32 + kgrp) * 2) ^ ((col & 7) << 4);
      const bf16x8 b = *(const bf16x8*)((const char*)Wt + byte);
      acc[t8] = __builtin_amdgcn_mfma_f32_16x16x32_bf16(a[s], b, acc[t8], 0, 0, 0);
    }
  }

  // Epilogue: per-row absmax (shfl over the 16 channel-lanes) -> int8 quant.
  const int li = lane & 15;
  const int r0 = R0 + (lane >> 4) * 4;
#pragma unroll
  for (int i = 0; i < 4; ++i) {
    const int rr = r0 + i;
    float m = 0.f;
#pragma unroll
    for (int t8 = 0; t8 < 8; ++t8) m = fmaxf(m, fabsf(acc[t8][i]));
    m = fmaxf(m, __shfl_xor(m, 1));
    m = fmaxf(m, __shfl_xor(m, 2));
    m = fmaxf(m, __shfl_xor(m, 4));
    m = fmaxf(m, __shfl_xor(m, 8));
    const float inv = (m > 1e-20f) ? 127.f / m : 0.f;
    if (rr < n) {
      if (li == 0) scale[rr] = m * (1.f / 127.f);
#pragma unroll
      for (int t8 = 0; t8 < 8; ++t8) {
        // |acc|*inv <= 127 by construction; +128 -> [1,255], no clamp needed
        const float q = rintf(acc[t8][i] * inv) + 128.f;
        xwq[rr * CH + t8 * 16 + li] = (unsigned char)q;
      }
    }
  }
}

// ---------------------------------------------------------------------------
// Phase 2: SpMM, QUARTER-WAVE per row: 16 lanes own one row, 4 independent
// rows per wave (R6 lesson: keep many independent row-units; R5 audit:
// the 96-instr/row cross-lane butterfly cost as much as decode -> lane li
// now exclusively owns channels li*8..li*8+7, so acc reduction VANISHES).
// Per 16-edge chunk:
//   * meta: lane li loads edge (e0+li)'s col/val + scale gather (coalesced;
//     dummy slots c=0/vp=0 — R5-proven trick, no branches in decode)
//   * c/vp distributed via a wave-private LDS slab: 2 ds_write_b32 +
//     8 ds_read_b128 replaces 32 shfl broadcasts
//   * 16 gathers (u32x2 = 8 int8 channels/lane) batch-issued -> 16-deep MLP
//     per quarter, 4 quarters independent
//   * decode: f32x2 pk_fma, unconditional (vp=0 kills dummy contributions)
// -128 offset: scalar S quarter-reduced (4 shfl). Epilogue: every lane
// stores its 8 channels directly (bias+ReLU fused) — no masking, no shfl.
// ---------------------------------------------------------------------------
#define ACCD(word, j0, vv)                                                \
  do {                                                                    \
    f32x2 lo_, hi_;                                                       \
    lo_[0] = (float)((word) & 0xFFu);                                     \
    lo_[1] = (float)(((word) >> 8) & 0xFFu);                              \
    hi_[0] = (float)(((word) >> 16) & 0xFFu);                             \
    hi_[1] = (float)((word) >> 24);                                       \
    acc2[(j0)]     = __builtin_elementwise_fma(vv, lo_, acc2[(j0)]);      \
    acc2[(j0) + 1] = __builtin_elementwise_fma(vv, hi_, acc2[(j0) + 1]);  \
  } while (0)

#define ACC8PK(U, V)                                                      \
  do {                                                                    \
    const f32x2 vv_ = {(V), (V)};                                         \
    ACCD((U)[0], 0, vv_);                                                 \
    ACCD((U)[1], 2, vv_);                                                 \
  } while (0)

__global__ __launch_bounds__(256) void spmm_qwave(
    const unsigned char* __restrict__ xwq, const float* __restrict__ scale,
    const float* __restrict__ edge_val, const int* __restrict__ edge_col,
    const int* __restrict__ row_ptr, const float* __restrict__ bias,
    float* __restrict__ out, int n) {
  __shared__ int   cbuf[256];
  __shared__ float vbuf[256];
  const int tid = threadIdx.x;
  const int row = (int)((blockIdx.x * 256 + tid) >> 4);
  if (row >= n) return;
  const int li    = tid & 15;    // lane-in-quarter: owns channels li*8..li*8+7
  const int qbase = tid & ~15;   // quarter's LDS base
  const u32x2* __restrict__ xw2 = (const u32x2*)xwq;  // 16 u32x2 per row

  const int start = row_ptr[row], end = row_ptr[row + 1];

  f32x2 acc2[4];
#pragma unroll
  for (int j = 0; j < 4; ++j) acc2[j] = (f32x2){0.f, 0.f};
  float S = 0.f;  // per-lane sum of vp (offset correction)

  for (int e0 = start; e0 < end; e0 += 16) {
    // meta: one edge per lane (16 consecutive edges of MY row)
    const int e = e0 + li;
    int   c_my = 0;
    float vp_my = 0.f;
    if (e < end) {
      c_my = __builtin_nontemporal_load(edge_col + e);
      vp_my = __builtin_nontemporal_load(edge_val + e) * scale[c_my];
    }
    S += vp_my;
    cbuf[tid] = c_my;     // wave-private slab: no barrier needed,
    vbuf[tid] = vp_my;    // in-wave DS ordering via lgkmcnt

    // batch-issue all 16 gathers (read c 4-at-a-time via ds_read_b128)
    u32x2 u[16];
#pragma unroll
    for (int it4 = 0; it4 < 4; ++it4) {
      const int4 c4 = *(const int4*)&cbuf[qbase + it4 * 4];
      u[it4 * 4 + 0] = xw2[c4.x * 16 + li];
      u[it4 * 4 + 1] = xw2[c4.y * 16 + li];
      u[it4 * 4 + 2] = xw2[c4.z * 16 + li];
      u[it4 * 4 + 3] = xw2[c4.w * 16 + li];
    }

    // decode: unconditional, vp=0 kills dummy slots
#pragma unroll
    for (int it4 = 0; it4 < 4; ++it4) {
      const f32x4 v4 = *(const f32x4*)&vbuf[qbase + it4 * 4];
      ACC8PK(u[it4 * 4 + 0], v4[0]);
      ACC8PK(u[it4 * 4 + 1], v4[1]);
      ACC8PK(u[it4 * 4 + 2], v4[2]);
      ACC8PK(u[it4 * 4 + 3], v4[3]);
    }
  }

  // S over the quarter's 16 lanes (each owned distinct edges)
  S += __shfl_xor(S, 1);
  S += __shfl_xor(S, 2);
  S += __shfl_xor(S, 4);
  S += __shfl_xor(S, 8);

  // epilogue: lane-local 8 channels, bias+ReLU, direct store — no masking
  const float off = 128.f * S;
  const float* a = (const float*)acc2;
  const int cb = li * 8;
  const f32x4 b0 = *(const f32x4*)&bias[cb];
  const f32x4 b1 = *(const f32x4*)&bias[cb + 4];
  f32x4 o0, o1;
  o0[0] = fmaxf(a[0] - off + b0[0], 0.f);
  o0[1] = fmaxf(a[1] - off + b0[1], 0.f);
  o0[2] = fmaxf(a[2] - off + b0[2], 0.f);
  o0[3] = fmaxf(a[3] - off + b0[3], 0.f);
  o1[0] = fmaxf(a[4] - off + b1[0], 0.f);
  o1[1] = fmaxf(a[5] - off + b1[1], 0.f);
  o1[2] = fmaxf(a[6] - off + b1[2], 0.f);
  o1[3] = fmaxf(a[7] - off + b1[3], 0.f);
  __builtin_nontemporal_store(o0, (f32x4*)&out[(size_t)row * CH + cb]);
  __builtin_nontemporal_store(o1, (f32x4*)&out[(size_t)row * CH + cb + 4]);
}

extern "C" void kernel_launch(void* const* d_in, const int* in_sizes, int n_in,
                              void* d_out, int out_size, void* d_ws, size_t ws_size,
                              hipStream_t stream) {
  const float* x        = (const float*)d_in[0];
  const float* kernel   = (const float*)d_in[1];
  const float* bias     = (const float*)d_in[2];
  const float* edge_val = (const float*)d_in[3];
  const int*   edge_row = (const int*)d_in[4];
  const int*   edge_col = (const int*)d_in[5];
  float* out = (float*)d_out;

  const int n       = in_sizes[0] / F_IN;   // 100000
  const int n_edges = in_sizes[3];          // 3200000

  // ws layout: [xwq: n*CH int8 = 12.8 MB][scale: n f32][row_ptr: (n+1) int]
  unsigned char* xwq = (unsigned char*)d_ws;
  float* scale = (float*)((char*)d_ws + (size_t)n * CH);
  int* rowptr  = (int*)((char*)d_ws + (size_t)n * CH + (size_t)n * sizeof(float));

  // Phase 1 (fused): XW = X @ W (bf16 MFMA) + int8 quant + CSR row_ptr
  const int GB = (n + 127) / 128;
  const int RB = (n + 1 + 511) / 512;
  gemm_rowptr_fused<<<GB + RB, 512, 0, stream>>>(x, kernel, xwq, scale,
                                                 edge_row, rowptr,
                                                 n, n_edges, GB);

  // Phase 2: SpMM + bias + ReLU. 16 rows per 256-thr block (quarter-wave/row).
  const int blocks = (n * 16 + 255) / 256;
  spmm_qwave<<<blocks, 256, 0, stream>>>(xwq, scale, edge_val, edge_col,
                                         rowptr, bias, out, n);
}